// Round 8
// baseline (1463.730 us; speedup 1.0000x reference)
//
#include <hip/hip_runtime.h>
#include <cmath>

#define B_  16
#define SEQ 2048
#define DIM 1024
#define LDST 40              // legacy stride for g1 LDS tiles

typedef short  short8 __attribute__((ext_vector_type(8)));
typedef short  sh4    __attribute__((ext_vector_type(4)));
typedef float  f32x4  __attribute__((ext_vector_type(4)));

__device__ __forceinline__ unsigned short f2bf(float x) {
  unsigned u = __builtin_bit_cast(unsigned, x);
  return (unsigned short)((u + 0x7fffu + ((u >> 16) & 1u)) >> 16);   // RNE
}
__device__ __forceinline__ float bf2f(unsigned short h) {
  unsigned u = ((unsigned)h) << 16;
  return __builtin_bit_cast(float, u);
}

__device__ __forceinline__ void gl16(const void* g, void* l) {
  __builtin_amdgcn_global_load_lds(
      (const __attribute__((address_space(1))) void*)g,
      (__attribute__((address_space(3))) void*)l, 16, 0, 0);
}

// ---------------------------------------------------------------------------
// cvt_ctx: ctx f32 -> chi/clo bf16 planes (into d_out comp region)
// ---------------------------------------------------------------------------
__global__ __launch_bounds__(256) void cvt_ctx(const float* __restrict__ X,
                                               unsigned short* __restrict__ hi,
                                               unsigned short* __restrict__ lo) {
  const size_t N8 = (size_t)B_ * SEQ * DIM / 8;
  for (size_t i = (size_t)blockIdx.x * 256 + threadIdx.x; i < N8;
       i += (size_t)gridDim.x * 256) {
    const size_t base = i * 8;
    float4 a = *(const float4*)&X[base];
    float4 c = *(const float4*)&X[base + 4];
    const float xs[8] = {a.x, a.y, a.z, a.w, c.x, c.y, c.z, c.w};
    short8 h, l;
#pragma unroll
    for (int j = 0; j < 8; ++j) {
      unsigned short hh = f2bf(xs[j]);
      h[j] = (short)hh;
      l[j] = (short)f2bf(xs[j] - bf2f(hh));
    }
    *(short8*)&hi[base] = h;
    *(short8*)&lo[base] = l;
  }
}

// ---------------------------------------------------------------------------
// t_ctx: ctxT[b][d][s] bf16 = ctx[b][s][d]
// ---------------------------------------------------------------------------
__global__ __launch_bounds__(256) void t_ctx(const float* __restrict__ X,
                                             unsigned short* __restrict__ T) {
  __shared__ unsigned short L[64 * 72];
  const int t = threadIdx.x;
  const int d0 = blockIdx.x * 64, s0 = blockIdx.y * 64, b = blockIdx.z;
#pragma unroll
  for (int p = 0; p < 4; ++p) {
    const int sl = (t >> 4) + p * 16, d4 = (t & 15) * 4;
    float4 v = *(const float4*)&X[((size_t)b * SEQ + s0 + sl) * DIM + d0 + d4];
    sh4 o = {(short)f2bf(v.x), (short)f2bf(v.y), (short)f2bf(v.z), (short)f2bf(v.w)};
    *(sh4*)&L[sl * 72 + d4] = o;
  }
  __syncthreads();
#pragma unroll
  for (int p = 0; p < 4; ++p) {
    const int dl = (t >> 4) + p * 16, s4 = (t & 15) * 4;
    sh4 o = {(short)L[(s4 + 0) * 72 + dl], (short)L[(s4 + 1) * 72 + dl],
             (short)L[(s4 + 2) * 72 + dl], (short)L[(s4 + 3) * 72 + dl]};
    *(sh4*)&T[((size_t)b * DIM + d0 + dl) * SEQ + s0 + s4] = o;
  }
}

// ---------------------------------------------------------------------------
// G1: z[r][d] = sum_e query[r][e] * W[d][e]  (unchanged)
// ---------------------------------------------------------------------------
__global__ __launch_bounds__(256) void g1_z(const float* __restrict__ Q,
                                            const float* __restrict__ W,
                                            unsigned short* __restrict__ zhi,
                                            unsigned short* __restrict__ zlo) {
  __shared__ unsigned short Ah[128 * LDST], Al[128 * LDST];
  __shared__ unsigned short Bh[128 * LDST], Bl[128 * LDST];
  const int tid = threadIdx.x;
  const int m0 = blockIdx.y * 128, n0 = blockIdx.x * 128;
  const int wave = tid >> 6, lane = tid & 63;
  const int wm = (wave >> 1) * 64, wn = (wave & 1) * 64;
  const int rl = tid & 127;

  const float* srow = (tid < 128) ? Q + (size_t)(m0 + rl) * DIM
                                  : W + (size_t)(n0 + rl) * DIM;
  unsigned short* th = (tid < 128) ? Ah : Bh;
  unsigned short* tl = (tid < 128) ? Al : Bl;

  f32x4 acc[4][4];
#pragma unroll
  for (int i = 0; i < 4; ++i)
#pragma unroll
    for (int j = 0; j < 4; ++j) acc[i][j] = (f32x4){0.f, 0.f, 0.f, 0.f};

  for (int kc = 0; kc < DIM; kc += 32) {
    float4 fv[8];
#pragma unroll
    for (int j = 0; j < 8; ++j) fv[j] = *(const float4*)&srow[kc + j * 4];
    __syncthreads();
    short8 hv[4], lv[4];
#pragma unroll
    for (int j = 0; j < 8; ++j) {
      const float x[4] = {fv[j].x, fv[j].y, fv[j].z, fv[j].w};
#pragma unroll
      for (int c = 0; c < 4; ++c) {
        unsigned short h = f2bf(x[c]);
        unsigned short l = f2bf(x[c] - bf2f(h));
        hv[j >> 1][(j & 1) * 4 + c] = (short)h;
        lv[j >> 1][(j & 1) * 4 + c] = (short)l;
      }
    }
#pragma unroll
    for (int j = 0; j < 4; ++j) {
      *(short8*)&th[rl * LDST + j * 8] = hv[j];
      *(short8*)&tl[rl * LDST + j * 8] = lv[j];
    }
    __syncthreads();

    short8 ah[4], al[4], bh[4], bl[4];
#pragma unroll
    for (int f = 0; f < 4; ++f) {
      const int ao = (wm + f * 16 + (lane & 15)) * LDST + (lane >> 4) * 8;
      const int bo = (wn + f * 16 + (lane & 15)) * LDST + (lane >> 4) * 8;
      ah[f] = *(const short8*)&Ah[ao];  al[f] = *(const short8*)&Al[ao];
      bh[f] = *(const short8*)&Bh[bo];  bl[f] = *(const short8*)&Bl[bo];
    }
#pragma unroll
    for (int i = 0; i < 4; ++i)
#pragma unroll
      for (int j = 0; j < 4; ++j) {
        acc[i][j] = __builtin_amdgcn_mfma_f32_16x16x32_bf16(ah[i], bh[j], acc[i][j], 0, 0, 0);
        acc[i][j] = __builtin_amdgcn_mfma_f32_16x16x32_bf16(al[i], bh[j], acc[i][j], 0, 0, 0);
        acc[i][j] = __builtin_amdgcn_mfma_f32_16x16x32_bf16(ah[i], bl[j], acc[i][j], 0, 0, 0);
      }
  }
#pragma unroll
  for (int i = 0; i < 4; ++i)
#pragma unroll
    for (int j = 0; j < 4; ++j)
#pragma unroll
      for (int r = 0; r < 4; ++r) {
        const int row = m0 + wm + i * 16 + (lane >> 4) * 4 + r;
        const int col = n0 + wn + j * 16 + (lane & 15);
        const float v = acc[i][j][r];
        const unsigned short h = f2bf(v);
        zhi[(size_t)row * DIM + col] = h;
        zlo[(size_t)row * DIM + col] = f2bf(v - bf2f(h));
      }
}

// ---------------------------------------------------------------------------
// G2 (256x256 tile): scores[q][b][s] = sum_d z[q*B_+b][d] * ctx[b][s][d]
// 512 threads / 8 waves (2m x 4n), wave tile 128(s) x 64(q), BK=32.
// 4 planes x 16KB = 64KB LDS, single-buffered 2-barrier loop (proven).
// XOR-swizzle pair: pre-swizzled gl16 source + swizzled frag read.
// ---------------------------------------------------------------------------
#define G2GRID 1024          // 8 s-tiles x 8 q-tiles x 16 batches
__global__ __launch_bounds__(512, 2) void g2_scores(const unsigned short* __restrict__ zhi,
                                                    const unsigned short* __restrict__ zlo,
                                                    const unsigned short* __restrict__ chi,
                                                    const unsigned short* __restrict__ clo,
                                                    float* __restrict__ Sc) {
  __shared__ unsigned short Sh[256 * 32], Sl[256 * 32];   // ctx (s-rows)
  __shared__ unsigned short Qh[256 * 32], Ql[256 * 32];   // z (q-rows)
  const int tid = threadIdx.x, lane = tid & 63, wave = tid >> 6;

  const int lin = blockIdx.x;
  const int swz = (lin & 7) * (G2GRID / 8) + (lin >> 3);
  const int b   = swz >> 6;
  const int tile = swz & 63;
  const int s0 = (tile >> 3) * 256;
  const int q0 = (tile & 7) * 256;

  const int wm = (wave >> 2) * 128;   // s-offset of wave tile
  const int wn = (wave & 3) * 64;     // q-offset

  const int r_sub = lane >> 2;
  const int c_sub = (((lane & 3) ^ ((lane >> 3) & 3))) * 8;   // pre-swizzled source col

  // staging: each wave owns 128 rows of one plane (8 x gl16 per K-step)
  const int plane_id = wave >> 1;            // 0:chi 1:clo 2:zhi 3:zlo
  const int rowoff   = (wave & 1) * 128;
  const unsigned short* plane = (plane_id == 0) ? chi : (plane_id == 1) ? clo
                              : (plane_id == 2) ? zhi : zlo;
  const size_t gbase  = (plane_id < 2) ? ((size_t)b * SEQ + s0 + rowoff) * DIM
                                       : ((size_t)(q0 + rowoff) * B_ + b) * DIM;
  const size_t gpitch = (plane_id < 2) ? (size_t)DIM : (size_t)B_ * DIM;
  const unsigned short* gp = plane + gbase + (size_t)r_sub * gpitch + c_sub;
  unsigned short* lbase = ((plane_id == 0) ? Sh : (plane_id == 1) ? Sl
                         : (plane_id == 2) ? Qh : Ql) + rowoff * 32;

  f32x4 acc[8][4];
#pragma unroll
  for (int i = 0; i < 8; ++i)
#pragma unroll
    for (int j = 0; j < 4; ++j) acc[i][j] = (f32x4){0.f, 0.f, 0.f, 0.f};

  for (int kc = 0; kc < DIM; kc += 32) {
#pragma unroll
    for (int it = 0; it < 8; ++it)
      gl16(gp + (size_t)it * 16 * gpitch + kc, lbase + it * 512);
    __syncthreads();

    short8 qh_[4], ql_[4];
#pragma unroll
    for (int j = 0; j < 4; ++j) {
      const int rb = wn + j * 16 + (lane & 15);
      const int qo = rb * 32 + (((lane >> 4) ^ ((rb >> 1) & 3))) * 8;
      qh_[j] = *(const short8*)&Qh[qo];
      ql_[j] = *(const short8*)&Ql[qo];
    }
#pragma unroll
    for (int i = 0; i < 8; ++i) {
      const int ra = wm + i * 16 + (lane & 15);
      const int so = ra * 32 + (((lane >> 4) ^ ((ra >> 1) & 3))) * 8;
      const short8 shf = *(const short8*)&Sh[so];
      const short8 slf = *(const short8*)&Sl[so];
#pragma unroll
      for (int j = 0; j < 4; ++j) {
        acc[i][j] = __builtin_amdgcn_mfma_f32_16x16x32_bf16(shf, qh_[j], acc[i][j], 0, 0, 0);
        acc[i][j] = __builtin_amdgcn_mfma_f32_16x16x32_bf16(slf, qh_[j], acc[i][j], 0, 0, 0);
        acc[i][j] = __builtin_amdgcn_mfma_f32_16x16x32_bf16(shf, ql_[j], acc[i][j], 0, 0, 0);
      }
    }
    __syncthreads();
  }

#pragma unroll
  for (int i = 0; i < 8; ++i)
#pragma unroll
    for (int j = 0; j < 4; ++j) {
      const int s = s0 + wm + i * 16 + (lane >> 4) * 4;
      const int q = q0 + wn + j * 16 + (lane & 15);
      f32x4 v = {acc[i][j][0], acc[i][j][1], acc[i][j][2], acc[i][j][3]};
      __builtin_nontemporal_store(v, (f32x4*)&Sc[((size_t)q * B_ + b) * SEQ + s]);
    }
}

// ---------------------------------------------------------------------------
// softmax: in-place, float4-vectorized
// ---------------------------------------------------------------------------
__global__ __launch_bounds__(256) void kernel_softmax(float* __restrict__ attn,
                                                      const int* __restrict__ mask) {
  const int row = blockIdx.x;       // q*B_ + b
  const int b = row & (B_ - 1);
  float* p = attn + (size_t)row * SEQ;
  const int* m = mask + (size_t)b * SEQ;
  const int t = threadIdx.x;

  float4 va = *(const float4*)&p[t * 8];
  float4 vb = *(const float4*)&p[t * 8 + 4];
  int4 ma = *(const int4*)&m[t * 8];
  int4 mb = *(const int4*)&m[t * 8 + 4];
  float v[8] = {ma.x ? -1e30f : va.x, ma.y ? -1e30f : va.y,
                ma.z ? -1e30f : va.z, ma.w ? -1e30f : va.w,
                mb.x ? -1e30f : vb.x, mb.y ? -1e30f : vb.y,
                mb.z ? -1e30f : vb.z, mb.w ? -1e30f : vb.w};
  float mx = -INFINITY;
#pragma unroll
  for (int i = 0; i < 8; ++i) mx = fmaxf(mx, v[i]);
#pragma unroll
  for (int off = 32; off > 0; off >>= 1) mx = fmaxf(mx, __shfl_xor(mx, off));
  __shared__ float redmax[4];
  __shared__ float redsum[4];
  if ((t & 63) == 0) redmax[t >> 6] = mx;
  __syncthreads();
  mx = fmaxf(fmaxf(redmax[0], redmax[1]), fmaxf(redmax[2], redmax[3]));

  float sum = 0.f;
#pragma unroll
  for (int i = 0; i < 8; ++i) {
    v[i] = __expf(v[i] - mx);
    sum += v[i];
  }
#pragma unroll
  for (int off = 32; off > 0; off >>= 1) sum += __shfl_xor(sum, off);
  if ((t & 63) == 0) redsum[t >> 6] = sum;
  __syncthreads();
  sum = (redsum[0] + redsum[1]) + (redsum[2] + redsum[3]);

  const bool allmasked = (mx < -1e29f);
  const float inv = allmasked ? 0.f : 1.f / sum;
  float4 oa = {v[0] * inv, v[1] * inv, v[2] * inv, v[3] * inv};
  float4 ob = {v[4] * inv, v[5] * inv, v[6] * inv, v[7] * inv};
  *(float4*)&p[t * 8] = oa;
  *(float4*)&p[t * 8 + 4] = ob;
}

// ---------------------------------------------------------------------------
// G3 (256x256 tile): comp[q][b][d] = sum_s attn[q][b][s] * ctx[b][s][d]
// A = ctxT d-rows (gl16, pre-swizzled source), B = attn f32 -> bf16 reg-staged
// (swizzled ds_write). 2 planes = 32KB LDS, single-buffered 2-barrier loop.
// ---------------------------------------------------------------------------
#define G3GRID 512           // 4 d-tiles x 8 q-tiles x 16 batches
__global__ __launch_bounds__(512, 2) void g3_comp(const float* __restrict__ attn,
                                                  const unsigned short* __restrict__ ctxT,
                                                  float* __restrict__ Out) {
  __shared__ unsigned short Ad[256 * 32];   // ctxT tile (d-rows)
  __shared__ unsigned short Bq[256 * 32];   // attn tile (q-rows, bf16)
  const int tid = threadIdx.x, lane = tid & 63, wave = tid >> 6;

  const int lin = blockIdx.x;
  const int swz = (lin & 7) * (G3GRID / 8) + (lin >> 3);
  const int b   = swz >> 5;
  const int tile = swz & 31;
  const int d0 = (tile >> 3) * 256;
  const int q0 = (tile & 7) * 256;

  const int wm = (wave >> 2) * 128;   // d-offset
  const int wn = (wave & 3) * 64;     // q-offset

  const int r_sub = lane >> 2;
  const int c_sub = (((lane & 3) ^ ((lane >> 3) & 3))) * 8;

  // A staging: wave stages d-rows [wave*32, wave*32+32)
  const unsigned short* agp =
      ctxT + ((size_t)b * DIM + d0 + wave * 32 + r_sub) * SEQ + c_sub;

  // B reg-staging geometry: thread pair per q-row
  const int qrow = tid >> 1, shalf = (tid & 1) * 16;
  const float* arow = attn + ((size_t)(q0 + qrow) * B_ + b) * SEQ;
  const int qsw = (qrow >> 1) & 3;
  const int bo0 = qrow * 32 + ((((tid & 1) * 2 + 0)) ^ qsw) * 8;
  const int bo1 = qrow * 32 + ((((tid & 1) * 2 + 1)) ^ qsw) * 8;

  f32x4 acc[8][4];
#pragma unroll
  for (int i = 0; i < 8; ++i)
#pragma unroll
    for (int j = 0; j < 4; ++j) acc[i][j] = (f32x4){0.f, 0.f, 0.f, 0.f};

  for (int kc = 0; kc < SEQ; kc += 32) {
    float4 fv[4];
#pragma unroll
    for (int j = 0; j < 4; ++j) fv[j] = *(const float4*)&arow[kc + shalf + j * 4];
    gl16(agp + kc, &Ad[(wave * 32) * 32]);
    gl16(agp + (size_t)16 * SEQ + kc, &Ad[(wave * 32 + 16) * 32]);
    short8 b0, b1;
#pragma unroll
    for (int j = 0; j < 4; ++j) {
      const float x[4] = {fv[j].x, fv[j].y, fv[j].z, fv[j].w};
#pragma unroll
      for (int c = 0; c < 4; ++c) {
        const int e = j * 4 + c;
        if (e < 8) b0[e] = (short)f2bf(x[c]);
        else       b1[e - 8] = (short)f2bf(x[c]);
      }
    }
    *(short8*)&Bq[bo0] = b0;
    *(short8*)&Bq[bo1] = b1;
    __syncthreads();

    short8 bf_[4];
#pragma unroll
    for (int j = 0; j < 4; ++j) {
      const int rb = wn + j * 16 + (lane & 15);
      bf_[j] = *(const short8*)&Bq[rb * 32 + (((lane >> 4) ^ ((rb >> 1) & 3))) * 8];
    }
#pragma unroll
    for (int i = 0; i < 8; ++i) {
      const int ra = wm + i * 16 + (lane & 15);
      const short8 af = *(const short8*)&Ad[ra * 32 + (((lane >> 4) ^ ((ra >> 1) & 3))) * 8];
#pragma unroll
      for (int j = 0; j < 4; ++j)
        acc[i][j] = __builtin_amdgcn_mfma_f32_16x16x32_bf16(af, bf_[j], acc[i][j], 0, 0, 0);
    }
    __syncthreads();
  }

#pragma unroll
  for (int i = 0; i < 8; ++i)
#pragma unroll
    for (int j = 0; j < 4; ++j) {
      const int d = d0 + wm + i * 16 + (lane >> 4) * 4;
      const int q = q0 + wn + j * 16 + (lane & 15);
      f32x4 v = {acc[i][j][0], acc[i][j][1], acc[i][j][2], acc[i][j][3]};
      __builtin_nontemporal_store(v, (f32x4*)&Out[((size_t)q * B_ + b) * DIM + d]);
    }
}

extern "C" void kernel_launch(void* const* d_in, const int* in_sizes, int n_in,
                              void* d_out, int out_size, void* d_ws, size_t ws_size,
                              hipStream_t stream) {
  const float* context = (const float*)d_in[0];   // [B, SEQ, DIM]
  const float* query   = (const float*)d_in[1];   // [SEQ, B, DIM]
  const float* W       = (const float*)d_in[2];   // [DIM, DIM]
  const int*   mask    = (const int*)d_in[3];     // [B, SEQ] bool->int32

  float* attn = (float*)d_out;                     // [SEQ, B, SEQ]  (256 MiB)
  float* comp = attn + (size_t)SEQ * B_ * SEQ;     // [SEQ, B, DIM]  (128 MiB)

  unsigned short* chi = (unsigned short*)comp;                     // 64 MiB
  unsigned short* clo = chi + (size_t)B_ * SEQ * DIM;              // 64 MiB

  unsigned short* zhi  = (unsigned short*)d_ws;                    // 64 MiB
  unsigned short* zlo  = zhi + (size_t)SEQ * B_ * DIM;             // 64 MiB
  unsigned short* ctxT = (unsigned short*)d_ws;                    // reuses z after G2

  // 0) ctx -> bf16 hi/lo planes (comp region; dead until G3 overwrites)
  cvt_ctx<<<dim3(4096), 256, 0, stream>>>(context, chi, clo);
  // 1) z = W @ query (flat rows), bf16x2
  g1_z<<<dim3(DIM / 128, (SEQ * B_) / 128), 256, 0, stream>>>(query, W, zhi, zlo);
  // 2) scores -> attn region (256^2 tile)
  g2_scores<<<dim3(G2GRID), 512, 0, stream>>>(zhi, zlo, chi, clo, attn);
  // 2b) ctxT bf16 [b][d][s] into d_ws (z dead now)
  t_ctx<<<dim3(DIM / 64, SEQ / 64, B_), 256, 0, stream>>>(context, ctxT);
  // 3) masked softmax in place
  kernel_softmax<<<dim3(SEQ * B_), 256, 0, stream>>>(attn, mask);
  // 4) comp = attn @ ctx via ctxT (256^2 tile)
  g3_comp<<<dim3(G3GRID), 512, 0, stream>>>(attn, ctxT, comp);
}

// Round 10
// 1395.717 us; speedup vs baseline: 1.0487x; 1.0487x over previous
//
#include <hip/hip_runtime.h>
#include <cmath>

#define B_  16
#define SEQ 2048
#define DIM 1024
#define LDST 40              // legacy stride for g1 LDS tiles

typedef short  short8 __attribute__((ext_vector_type(8)));
typedef short  sh4    __attribute__((ext_vector_type(4)));
typedef float  f32x4  __attribute__((ext_vector_type(4)));

__device__ __forceinline__ unsigned short f2bf(float x) {
  unsigned u = __builtin_bit_cast(unsigned, x);
  return (unsigned short)((u + 0x7fffu + ((u >> 16) & 1u)) >> 16);   // RNE
}
__device__ __forceinline__ float bf2f(unsigned short h) {
  unsigned u = ((unsigned)h) << 16;
  return __builtin_bit_cast(float, u);
}

__device__ __forceinline__ void gl16(const void* g, void* l) {
  __builtin_amdgcn_global_load_lds(
      (const __attribute__((address_space(1))) void*)g,
      (__attribute__((address_space(3))) void*)l, 16, 0, 0);
}

#define SCHEDB __builtin_amdgcn_sched_barrier(0)
#define SBAR   __builtin_amdgcn_s_barrier()

// ---------------------------------------------------------------------------
// cvt_ctx: ctx f32 -> chi/clo bf16 planes (into d_out comp region)
// ---------------------------------------------------------------------------
__global__ __launch_bounds__(256) void cvt_ctx(const float* __restrict__ X,
                                               unsigned short* __restrict__ hi,
                                               unsigned short* __restrict__ lo) {
  const size_t N8 = (size_t)B_ * SEQ * DIM / 8;
  for (size_t i = (size_t)blockIdx.x * 256 + threadIdx.x; i < N8;
       i += (size_t)gridDim.x * 256) {
    const size_t base = i * 8;
    float4 a = *(const float4*)&X[base];
    float4 c = *(const float4*)&X[base + 4];
    const float xs[8] = {a.x, a.y, a.z, a.w, c.x, c.y, c.z, c.w};
    short8 h, l;
#pragma unroll
    for (int j = 0; j < 8; ++j) {
      unsigned short hh = f2bf(xs[j]);
      h[j] = (short)hh;
      l[j] = (short)f2bf(xs[j] - bf2f(hh));
    }
    *(short8*)&hi[base] = h;
    *(short8*)&lo[base] = l;
  }
}

// ---------------------------------------------------------------------------
// t_chi: ctxT[b][d][s] = transpose of chi[b][s][d]  (bf16 -> bf16, via LDS)
// ---------------------------------------------------------------------------
__global__ __launch_bounds__(256) void t_chi(const unsigned short* __restrict__ H,
                                             unsigned short* __restrict__ T) {
  __shared__ unsigned short L[64][72];
  const int t = threadIdx.x;
  const int d0 = blockIdx.x * 64, s0 = blockIdx.y * 64, b = blockIdx.z;
  const int sl = t >> 2, dp = (t & 3) * 16;
  short8 v0 = *(const short8*)&H[((size_t)b * SEQ + s0 + sl) * DIM + d0 + dp];
  short8 v1 = *(const short8*)&H[((size_t)b * SEQ + s0 + sl) * DIM + d0 + dp + 8];
  *(short8*)&L[sl][dp] = v0;
  *(short8*)&L[sl][dp + 8] = v1;
  __syncthreads();
  const int dl = t >> 2, sp = (t & 3) * 16;
  short8 o0, o1;
#pragma unroll
  for (int k = 0; k < 8; ++k) {
    o0[k] = (short)L[sp + k][dl];
    o1[k] = (short)L[sp + 8 + k][dl];
  }
  *(short8*)&T[((size_t)b * DIM + d0 + dl) * SEQ + s0 + sp] = o0;
  *(short8*)&T[((size_t)b * DIM + d0 + dl) * SEQ + s0 + sp + 8] = o1;
}

// ---------------------------------------------------------------------------
// G1: z[r][d] = sum_e query[r][e] * W[d][e]  (R6-proven)
// ---------------------------------------------------------------------------
__global__ __launch_bounds__(256) void g1_z(const float* __restrict__ Q,
                                            const float* __restrict__ W,
                                            unsigned short* __restrict__ zhi,
                                            unsigned short* __restrict__ zlo) {
  __shared__ unsigned short Ah[128 * LDST], Al[128 * LDST];
  __shared__ unsigned short Bh[128 * LDST], Bl[128 * LDST];
  const int tid = threadIdx.x;
  const int m0 = blockIdx.y * 128, n0 = blockIdx.x * 128;
  const int wave = tid >> 6, lane = tid & 63;
  const int wm = (wave >> 1) * 64, wn = (wave & 1) * 64;
  const int rl = tid & 127;

  const float* srow = (tid < 128) ? Q + (size_t)(m0 + rl) * DIM
                                  : W + (size_t)(n0 + rl) * DIM;
  unsigned short* th = (tid < 128) ? Ah : Bh;
  unsigned short* tl = (tid < 128) ? Al : Bl;

  f32x4 acc[4][4];
#pragma unroll
  for (int i = 0; i < 4; ++i)
#pragma unroll
    for (int j = 0; j < 4; ++j) acc[i][j] = (f32x4){0.f, 0.f, 0.f, 0.f};

  for (int kc = 0; kc < DIM; kc += 32) {
    float4 fv[8];
#pragma unroll
    for (int j = 0; j < 8; ++j) fv[j] = *(const float4*)&srow[kc + j * 4];
    __syncthreads();
    short8 hv[4], lv[4];
#pragma unroll
    for (int j = 0; j < 8; ++j) {
      const float x[4] = {fv[j].x, fv[j].y, fv[j].z, fv[j].w};
#pragma unroll
      for (int c = 0; c < 4; ++c) {
        unsigned short h = f2bf(x[c]);
        unsigned short l = f2bf(x[c] - bf2f(h));
        hv[j >> 1][(j & 1) * 4 + c] = (short)h;
        lv[j >> 1][(j & 1) * 4 + c] = (short)l;
      }
    }
#pragma unroll
    for (int j = 0; j < 4; ++j) {
      *(short8*)&th[rl * LDST + j * 8] = hv[j];
      *(short8*)&tl[rl * LDST + j * 8] = lv[j];
    }
    __syncthreads();

    short8 ah[4], al[4], bh[4], bl[4];
#pragma unroll
    for (int f = 0; f < 4; ++f) {
      const int ao = (wm + f * 16 + (lane & 15)) * LDST + (lane >> 4) * 8;
      const int bo = (wn + f * 16 + (lane & 15)) * LDST + (lane >> 4) * 8;
      ah[f] = *(const short8*)&Ah[ao];  al[f] = *(const short8*)&Al[ao];
      bh[f] = *(const short8*)&Bh[bo];  bl[f] = *(const short8*)&Bl[bo];
    }
#pragma unroll
    for (int i = 0; i < 4; ++i)
#pragma unroll
      for (int j = 0; j < 4; ++j) {
        acc[i][j] = __builtin_amdgcn_mfma_f32_16x16x32_bf16(ah[i], bh[j], acc[i][j], 0, 0, 0);
        acc[i][j] = __builtin_amdgcn_mfma_f32_16x16x32_bf16(al[i], bh[j], acc[i][j], 0, 0, 0);
        acc[i][j] = __builtin_amdgcn_mfma_f32_16x16x32_bf16(ah[i], bl[j], acc[i][j], 0, 0, 0);
      }
  }
#pragma unroll
  for (int i = 0; i < 4; ++i)
#pragma unroll
    for (int j = 0; j < 4; ++j)
#pragma unroll
      for (int r = 0; r < 4; ++r) {
        const int row = m0 + wm + i * 16 + (lane >> 4) * 4 + r;
        const int col = n0 + wn + j * 16 + (lane & 15);
        const float v = acc[i][j][r];
        const unsigned short h = f2bf(v);
        zhi[(size_t)row * DIM + col] = h;
        zlo[(size_t)row * DIM + col] = f2bf(v - bf2f(h));
      }
}

// ---------------------------------------------------------------------------
// G2 (256x256, 4-phase counted-vmcnt pipeline, RACE-FIXED):
// main loop t=0..30 (full prefetch); tile 31 peeled as a drain epilogue
// (vmcnt(0)+barrier then barrier-free compute). Steady-state waits:
// p1 vmcnt(2), p4 vmcnt(4); granule order A {0,1}{2,3}{4,5}{6,7},
// B {0,1}{4,5}{2,3}{6,7} (phase-1 B-reads hit rows wn..wn+31 for
// wn in {0,64,128,192} = granules {0,1},{4,5} of each 128-row half).
// ---------------------------------------------------------------------------
#define G2GRID 1024
__global__ __launch_bounds__(512, 2) void g2_scores(
    const unsigned short* __restrict__ zhi, const unsigned short* __restrict__ zlo,
    const unsigned short* __restrict__ chi, const unsigned short* __restrict__ clo,
    float* __restrict__ Sc) {
  __shared__ unsigned short LB[2][4][256 * 32];   // [slot][plane][row*32+col] = 128 KB
  const int tid = threadIdx.x, lane = tid & 63, wave = tid >> 6;

  const int lin = blockIdx.x;
  const int swz = (lin & 7) * (G2GRID / 8) + (lin >> 3);
  const int b = swz >> 6;
  const int tile = swz & 63;
  const int s0 = (tile >> 3) * 256, q0 = (tile & 7) * 256;

  const int wm = (wave >> 2) * 128;   // s-offset of wave tile
  const int wn = (wave & 3) * 64;     // q-offset

  const int r_sub = lane >> 2;
  const int c_sub = ((lane & 3) ^ ((lane >> 3) & 3)) * 8;   // pre-swizzled source col

  const int plane_id = wave >> 1;     // 0:Sh(chi) 1:Sl(clo) 2:Qh(zhi) 3:Ql(zlo)
  const int h = wave & 1;             // row-half this wave stages
  const unsigned short* plane = (plane_id == 0) ? chi : (plane_id == 1) ? clo
                              : (plane_id == 2) ? zhi : zlo;
  const size_t gbase = (plane_id < 2) ? ((size_t)b * SEQ + s0 + h * 128) * DIM
                                      : ((size_t)(q0 + h * 128) * B_ + b) * DIM;
  const size_t gpitch = (plane_id < 2) ? (size_t)DIM : (size_t)B_ * DIM;
  const unsigned short* gp = plane + gbase + (size_t)r_sub * gpitch + c_sub;
  const int ldsbase = h * 128 * 32;   // short offset within plane

  f32x4 acc[8][4];
#pragma unroll
  for (int i = 0; i < 8; ++i)
#pragma unroll
    for (int j = 0; j < 4; ++j) acc[i][j] = (f32x4){0.f, 0.f, 0.f, 0.f};

  // prologue: stage tile 0 -> slot 0, drain, publish
  {
    unsigned short* dst = &LB[0][plane_id][0] + ldsbase;
#pragma unroll
    for (int it = 0; it < 8; ++it)
      gl16(gp + (size_t)it * 16 * gpitch, dst + it * 512);
  }
  asm volatile("s_waitcnt vmcnt(0)" ::: "memory");
  SBAR; SCHEDB;

  short8 ah[4], al[4], qh[4], ql[4];
  const int aFirst[4] = {0, 2, 4, 6};
  const int bFirst[4] = {0, 4, 2, 6};

  for (int t = 0; t < 31; ++t) {
    const unsigned short* Shp = &LB[t & 1][0][0];
    const unsigned short* Slp = &LB[t & 1][1][0];
    const unsigned short* Qhp = &LB[t & 1][2][0];
    const unsigned short* Qlp = &LB[t & 1][3][0];
    unsigned short* dstP = &LB[(t + 1) & 1][plane_id][0] + ldsbase;
    const size_t kn = (size_t)(t + 1) * 32;

    // ---------------- phase 1: A i0..3, B j0..1 ----------------
#pragma unroll
    for (int i = 0; i < 4; ++i) {
      const int ra = wm + i * 16 + (lane & 15);
      const int so = ra * 32 + (((lane >> 4) ^ ((ra >> 1) & 3)) * 8);
      ah[i] = *(const short8*)&Shp[so];
      al[i] = *(const short8*)&Slp[so];
    }
#pragma unroll
    for (int j = 0; j < 2; ++j) {
      const int rb = wn + j * 16 + (lane & 15);
      const int qo = rb * 32 + (((lane >> 4) ^ ((rb >> 1) & 3)) * 8);
      qh[j] = *(const short8*)&Qhp[qo];
      ql[j] = *(const short8*)&Qlp[qo];
    }
    {
      const int i0 = (plane_id >= 2) ? bFirst[0] : aFirst[0];
      gl16(gp + (size_t)i0 * 16 * gpitch + kn, dstP + i0 * 512);
      gl16(gp + (size_t)(i0 + 1) * 16 * gpitch + kn, dstP + (i0 + 1) * 512);
    }
    asm volatile("s_waitcnt vmcnt(2)" ::: "memory");
    SBAR; SCHEDB;
    asm volatile("s_waitcnt lgkmcnt(0)" ::: "memory");
    SCHEDB;
    __builtin_amdgcn_s_setprio(1);
#pragma unroll
    for (int i = 0; i < 4; ++i)
#pragma unroll
      for (int j = 0; j < 2; ++j) {
        acc[i][j] = __builtin_amdgcn_mfma_f32_16x16x32_bf16(ah[i], qh[j], acc[i][j], 0, 0, 0);
        acc[i][j] = __builtin_amdgcn_mfma_f32_16x16x32_bf16(al[i], qh[j], acc[i][j], 0, 0, 0);
        acc[i][j] = __builtin_amdgcn_mfma_f32_16x16x32_bf16(ah[i], ql[j], acc[i][j], 0, 0, 0);
      }
    __builtin_amdgcn_s_setprio(0);

    // ---------------- phase 2: B j2..3 ----------------
#pragma unroll
    for (int j = 2; j < 4; ++j) {
      const int rb = wn + j * 16 + (lane & 15);
      const int qo = rb * 32 + (((lane >> 4) ^ ((rb >> 1) & 3)) * 8);
      qh[j] = *(const short8*)&Qhp[qo];
      ql[j] = *(const short8*)&Qlp[qo];
    }
    {
      const int i0 = (plane_id >= 2) ? bFirst[1] : aFirst[1];
      gl16(gp + (size_t)i0 * 16 * gpitch + kn, dstP + i0 * 512);
      gl16(gp + (size_t)(i0 + 1) * 16 * gpitch + kn, dstP + (i0 + 1) * 512);
    }
    SBAR; SCHEDB;
    asm volatile("s_waitcnt lgkmcnt(0)" ::: "memory");
    SCHEDB;
    __builtin_amdgcn_s_setprio(1);
#pragma unroll
    for (int i = 0; i < 4; ++i)
#pragma unroll
      for (int j = 2; j < 4; ++j) {
        acc[i][j] = __builtin_amdgcn_mfma_f32_16x16x32_bf16(ah[i], qh[j], acc[i][j], 0, 0, 0);
        acc[i][j] = __builtin_amdgcn_mfma_f32_16x16x32_bf16(al[i], qh[j], acc[i][j], 0, 0, 0);
        acc[i][j] = __builtin_amdgcn_mfma_f32_16x16x32_bf16(ah[i], ql[j], acc[i][j], 0, 0, 0);
      }
    __builtin_amdgcn_s_setprio(0);

    // ---------------- phase 3: A i4..7, B j0..1 ----------------
#pragma unroll
    for (int i = 0; i < 4; ++i) {
      const int ra = wm + (i + 4) * 16 + (lane & 15);
      const int so = ra * 32 + (((lane >> 4) ^ ((ra >> 1) & 3)) * 8);
      ah[i] = *(const short8*)&Shp[so];
      al[i] = *(const short8*)&Slp[so];
    }
    {
      const int i0 = (plane_id >= 2) ? bFirst[2] : aFirst[2];
      gl16(gp + (size_t)i0 * 16 * gpitch + kn, dstP + i0 * 512);
      gl16(gp + (size_t)(i0 + 1) * 16 * gpitch + kn, dstP + (i0 + 1) * 512);
    }
    SBAR; SCHEDB;
    asm volatile("s_waitcnt lgkmcnt(0)" ::: "memory");
    SCHEDB;
    __builtin_amdgcn_s_setprio(1);
#pragma unroll
    for (int i = 0; i < 4; ++i)
#pragma unroll
      for (int j = 0; j < 2; ++j) {
        acc[i + 4][j] = __builtin_amdgcn_mfma_f32_16x16x32_bf16(ah[i], qh[j], acc[i + 4][j], 0, 0, 0);
        acc[i + 4][j] = __builtin_amdgcn_mfma_f32_16x16x32_bf16(al[i], qh[j], acc[i + 4][j], 0, 0, 0);
        acc[i + 4][j] = __builtin_amdgcn_mfma_f32_16x16x32_bf16(ah[i], ql[j], acc[i + 4][j], 0, 0, 0);
      }
    __builtin_amdgcn_s_setprio(0);

    // ---------------- phase 4: A i4..7, B j2..3 ----------------
    {
      const int i0 = (plane_id >= 2) ? bFirst[3] : aFirst[3];
      gl16(gp + (size_t)i0 * 16 * gpitch + kn, dstP + i0 * 512);
      gl16(gp + (size_t)(i0 + 1) * 16 * gpitch + kn, dstP + (i0 + 1) * 512);
    }
    asm volatile("s_waitcnt vmcnt(4)" ::: "memory");
    SBAR; SCHEDB;
    __builtin_amdgcn_s_setprio(1);
#pragma unroll
    for (int i = 0; i < 4; ++i)
#pragma unroll
      for (int j = 2; j < 4; ++j) {
        acc[i + 4][j] = __builtin_amdgcn_mfma_f32_16x16x32_bf16(ah[i], qh[j], acc[i + 4][j], 0, 0, 0);
        acc[i + 4][j] = __builtin_amdgcn_mfma_f32_16x16x32_bf16(al[i], qh[j], acc[i + 4][j], 0, 0, 0);
        acc[i + 4][j] = __builtin_amdgcn_mfma_f32_16x16x32_bf16(ah[i], ql[j], acc[i + 4][j], 0, 0, 0);
      }
    __builtin_amdgcn_s_setprio(0);
  }

  // ------------- epilogue: tile 31 (slot 1) — drain, publish, compute -------
  asm volatile("s_waitcnt vmcnt(0)" ::: "memory");
  SBAR; SCHEDB;
  {
    const unsigned short* Shp = &LB[1][0][0];
    const unsigned short* Slp = &LB[1][1][0];
    const unsigned short* Qhp = &LB[1][2][0];
    const unsigned short* Qlp = &LB[1][3][0];
#pragma unroll
    for (int j = 0; j < 4; ++j) {
      const int rb = wn + j * 16 + (lane & 15);
      const int qo = rb * 32 + (((lane >> 4) ^ ((rb >> 1) & 3)) * 8);
      qh[j] = *(const short8*)&Qhp[qo];
      ql[j] = *(const short8*)&Qlp[qo];
    }
#pragma unroll
    for (int half = 0; half < 2; ++half) {
#pragma unroll
      for (int i = 0; i < 4; ++i) {
        const int ra = wm + (half * 4 + i) * 16 + (lane & 15);
        const int so = ra * 32 + (((lane >> 4) ^ ((ra >> 1) & 3)) * 8);
        ah[i] = *(const short8*)&Shp[so];
        al[i] = *(const short8*)&Slp[so];
      }
      asm volatile("s_waitcnt lgkmcnt(0)" ::: "memory");
      SCHEDB;
#pragma unroll
      for (int i = 0; i < 4; ++i)
#pragma unroll
        for (int j = 0; j < 4; ++j) {
          acc[half * 4 + i][j] = __builtin_amdgcn_mfma_f32_16x16x32_bf16(ah[i], qh[j], acc[half * 4 + i][j], 0, 0, 0);
          acc[half * 4 + i][j] = __builtin_amdgcn_mfma_f32_16x16x32_bf16(al[i], qh[j], acc[half * 4 + i][j], 0, 0, 0);
          acc[half * 4 + i][j] = __builtin_amdgcn_mfma_f32_16x16x32_bf16(ah[i], ql[j], acc[half * 4 + i][j], 0, 0, 0);
        }
    }
  }

#pragma unroll
  for (int i = 0; i < 8; ++i)
#pragma unroll
    for (int j = 0; j < 4; ++j) {
      const int s = s0 + wm + i * 16 + (lane >> 4) * 4;
      const int q = q0 + wn + j * 16 + (lane & 15);
      f32x4 v = {acc[i][j][0], acc[i][j][1], acc[i][j][2], acc[i][j][3]};
      __builtin_nontemporal_store(v, (f32x4*)&Sc[((size_t)q * B_ + b) * SEQ + s]);
    }
}

// ---------------------------------------------------------------------------
// softmax: in-place, float4-vectorized
// ---------------------------------------------------------------------------
__global__ __launch_bounds__(256) void kernel_softmax(float* __restrict__ attn,
                                                      const int* __restrict__ mask) {
  const int row = blockIdx.x;       // q*B_ + b
  const int b = row & (B_ - 1);
  float* p = attn + (size_t)row * SEQ;
  const int* m = mask + (size_t)b * SEQ;
  const int t = threadIdx.x;

  float4 va = *(const float4*)&p[t * 8];
  float4 vb = *(const float4*)&p[t * 8 + 4];
  int4 ma = *(const int4*)&m[t * 8];
  int4 mb = *(const int4*)&m[t * 8 + 4];
  float v[8] = {ma.x ? -1e30f : va.x, ma.y ? -1e30f : va.y,
                ma.z ? -1e30f : va.z, ma.w ? -1e30f : va.w,
                mb.x ? -1e30f : vb.x, mb.y ? -1e30f : vb.y,
                mb.z ? -1e30f : vb.z, mb.w ? -1e30f : vb.w};
  float mx = -INFINITY;
#pragma unroll
  for (int i = 0; i < 8; ++i) mx = fmaxf(mx, v[i]);
#pragma unroll
  for (int off = 32; off > 0; off >>= 1) mx = fmaxf(mx, __shfl_xor(mx, off));
  __shared__ float redmax[4];
  __shared__ float redsum[4];
  if ((t & 63) == 0) redmax[t >> 6] = mx;
  __syncthreads();
  mx = fmaxf(fmaxf(redmax[0], redmax[1]), fmaxf(redmax[2], redmax[3]));

  float sum = 0.f;
#pragma unroll
  for (int i = 0; i < 8; ++i) {
    v[i] = __expf(v[i] - mx);
    sum += v[i];
  }
#pragma unroll
  for (int off = 32; off > 0; off >>= 1) sum += __shfl_xor(sum, off);
  if ((t & 63) == 0) redsum[t >> 6] = sum;
  __syncthreads();
  sum = (redsum[0] + redsum[1]) + (redsum[2] + redsum[3]);

  const bool allmasked = (mx < -1e29f);
  const float inv = allmasked ? 0.f : 1.f / sum;
  float4 oa = {v[0] * inv, v[1] * inv, v[2] * inv, v[3] * inv};
  float4 ob = {v[4] * inv, v[5] * inv, v[6] * inv, v[7] * inv};
  *(float4*)&p[t * 8] = oa;
  *(float4*)&p[t * 8 + 4] = ob;
}

// ---------------------------------------------------------------------------
// G3 (R6-proven 128^2): comp[q][b][d] = sum_s attn[q][b][s] * ctx[b][s][d]
// ---------------------------------------------------------------------------
__global__ __launch_bounds__(256) void g3_comp(const float* __restrict__ attn,
                                               const unsigned short* __restrict__ ctxT,
                                               float* __restrict__ Out) {
  __shared__ unsigned short Ad[128 * 32];
  __shared__ unsigned short Bq[128 * 32];
  const int tid = threadIdx.x, lane = tid & 63, wave = tid >> 6;
  const int b = blockIdx.z;
  const int d0 = blockIdx.x * 128, q0 = blockIdx.y * 128;
  const int wm = (wave >> 1) * 64;   // d
  const int wn = (wave & 1) * 64;    // q

  const int r_sub = lane >> 2;
  const int c_sub = (((lane & 3) ^ ((lane >> 3) & 3))) * 8;

  const unsigned short* agp =
      ctxT + ((size_t)b * DIM + d0 + wave * 32 + r_sub) * SEQ + c_sub;

  const int qrow = tid >> 1, shalf = (tid & 1) * 16;
  const float* arow = attn + ((size_t)(q0 + qrow) * B_ + b) * SEQ;
  const int qsw = (qrow >> 1) & 3;
  const int blk_base = (tid & 1) * 2;
  unsigned short* bdst0 = &Bq[qrow * 32 + ((blk_base + 0) ^ qsw) * 8];
  unsigned short* bdst1 = &Bq[qrow * 32 + ((blk_base + 1) ^ qsw) * 8];

  f32x4 acc[4][4];
#pragma unroll
  for (int i = 0; i < 4; ++i)
#pragma unroll
    for (int j = 0; j < 4; ++j) acc[i][j] = (f32x4){0.f, 0.f, 0.f, 0.f};

  for (int kc = 0; kc < SEQ; kc += 32) {
    float4 fv[4];
#pragma unroll
    for (int j = 0; j < 4; ++j) fv[j] = *(const float4*)&arow[kc + shalf + j * 4];
#pragma unroll
    for (int i = 0; i < 2; ++i) {
      const int rb = wave * 32 + i * 16;
      gl16(agp + (size_t)i * 16 * SEQ + kc, &Ad[rb * 32]);
    }
    short8 bv0, bv1;
#pragma unroll
    for (int j = 0; j < 4; ++j) {
      const float x[4] = {fv[j].x, fv[j].y, fv[j].z, fv[j].w};
#pragma unroll
      for (int c = 0; c < 4; ++c) {
        const int e = j * 4 + c;
        if (e < 8) bv0[e] = (short)f2bf(x[c]);
        else       bv1[e - 8] = (short)f2bf(x[c]);
      }
    }
    *(short8*)bdst0 = bv0;
    *(short8*)bdst1 = bv1;
    __syncthreads();

    short8 af[4], bf_[4];
#pragma unroll
    for (int f = 0; f < 4; ++f) {
      const int ra = wm + f * 16 + (lane & 15);
      const int rb = wn + f * 16 + (lane & 15);
      af[f]  = *(const short8*)&Ad[ra * 32 + (((lane >> 4) ^ ((ra >> 1) & 3))) * 8];
      bf_[f] = *(const short8*)&Bq[rb * 32 + (((lane >> 4) ^ ((rb >> 1) & 3))) * 8];
    }
#pragma unroll
    for (int i = 0; i < 4; ++i)
#pragma unroll
      for (int j = 0; j < 4; ++j)
        acc[i][j] = __builtin_amdgcn_mfma_f32_16x16x32_bf16(af[i], bf_[j], acc[i][j], 0, 0, 0);
    __syncthreads();
  }

#pragma unroll
  for (int i = 0; i < 4; ++i)
#pragma unroll
    for (int j = 0; j < 4; ++j) {
      const int d = d0 + wm + i * 16 + (lane >> 4) * 4;
      const int q = q0 + wn + j * 16 + (lane & 15);
      f32x4 v = {acc[i][j][0], acc[i][j][1], acc[i][j][2], acc[i][j][3]};
      __builtin_nontemporal_store(v, (f32x4*)&Out[((size_t)q * B_ + b) * DIM + d]);
    }
}

extern "C" void kernel_launch(void* const* d_in, const int* in_sizes, int n_in,
                              void* d_out, int out_size, void* d_ws, size_t ws_size,
                              hipStream_t stream) {
  const float* context = (const float*)d_in[0];   // [B, SEQ, DIM]
  const float* query   = (const float*)d_in[1];   // [SEQ, B, DIM]
  const float* W       = (const float*)d_in[2];   // [DIM, DIM]
  const int*   mask    = (const int*)d_in[3];     // [B, SEQ] bool->int32

  float* attn = (float*)d_out;                     // [SEQ, B, SEQ]  (256 MiB)
  float* comp = attn + (size_t)SEQ * B_ * SEQ;     // [SEQ, B, DIM]  (128 MiB)

  unsigned short* chi = (unsigned short*)comp;                     // 64 MiB
  unsigned short* clo = chi + (size_t)B_ * SEQ * DIM;              // 64 MiB

  unsigned short* zhi  = (unsigned short*)d_ws;                    // 64 MiB
  unsigned short* zlo  = zhi + (size_t)SEQ * B_ * DIM;             // 64 MiB
  unsigned short* ctxT = (unsigned short*)d_ws;                    // reuses z after G2

  // 0) ctx -> bf16 hi/lo planes (comp region; dead until G3 overwrites)
  cvt_ctx<<<dim3(4096), 256, 0, stream>>>(context, chi, clo);
  // 1) z = W @ query (flat rows), bf16x2
  g1_z<<<dim3(DIM / 128, (SEQ * B_) / 128), 256, 0, stream>>>(query, W, zhi, zlo);
  // 2) scores -> attn region (256^2, counted-vmcnt 4-phase pipeline, race-fixed)
  g2_scores<<<dim3(G2GRID), 512, 0, stream>>>(zhi, zlo, chi, clo, attn);
  // 2b) ctxT = transpose(chi) into d_ws (z dead now)
  t_chi<<<dim3(DIM / 64, SEQ / 64, B_), 256, 0, stream>>>(chi, ctxT);
  // 3) masked softmax in place
  kernel_softmax<<<dim3(SEQ * B_), 256, 0, stream>>>(attn, mask);
  // 4) comp = attn @ ctx via ctxT (128^2, R6 structure)
  g3_comp<<<dim3(DIM / 128, SEQ / 128, B_), 256, 0, stream>>>(attn, ctxT, comp);
}

// Round 11
// 1307.646 us; speedup vs baseline: 1.1194x; 1.0674x over previous
//
#include <hip/hip_runtime.h>
#include <cmath>

#define B_  16
#define SEQ 2048
#define DIM 1024
#define LDST 40              // legacy stride for g1 LDS tiles

typedef short  short8 __attribute__((ext_vector_type(8)));
typedef short  sh4    __attribute__((ext_vector_type(4)));
typedef float  f32x4  __attribute__((ext_vector_type(4)));

__device__ __forceinline__ unsigned short f2bf(float x) {
  unsigned u = __builtin_bit_cast(unsigned, x);
  return (unsigned short)((u + 0x7fffu + ((u >> 16) & 1u)) >> 16);   // RNE
}
__device__ __forceinline__ float bf2f(unsigned short h) {
  unsigned u = ((unsigned)h) << 16;
  return __builtin_bit_cast(float, u);
}

__device__ __forceinline__ void gl16(const void* g, void* l) {
  __builtin_amdgcn_global_load_lds(
      (const __attribute__((address_space(1))) void*)g,
      (__attribute__((address_space(3))) void*)l, 16, 0, 0);
}

// ---------------------------------------------------------------------------
// cvt_ctx: ctx f32 -> chi/clo bf16 planes (into d_out comp region)
// ---------------------------------------------------------------------------
__global__ __launch_bounds__(256) void cvt_ctx(const float* __restrict__ X,
                                               unsigned short* __restrict__ hi,
                                               unsigned short* __restrict__ lo) {
  const size_t N8 = (size_t)B_ * SEQ * DIM / 8;
  for (size_t i = (size_t)blockIdx.x * 256 + threadIdx.x; i < N8;
       i += (size_t)gridDim.x * 256) {
    const size_t base = i * 8;
    float4 a = *(const float4*)&X[base];
    float4 c = *(const float4*)&X[base + 4];
    const float xs[8] = {a.x, a.y, a.z, a.w, c.x, c.y, c.z, c.w};
    short8 h, l;
#pragma unroll
    for (int j = 0; j < 8; ++j) {
      unsigned short hh = f2bf(xs[j]);
      h[j] = (short)hh;
      l[j] = (short)f2bf(xs[j] - bf2f(hh));
    }
    *(short8*)&hi[base] = h;
    *(short8*)&lo[base] = l;
  }
}

// ---------------------------------------------------------------------------
// t_chi: ctxT[b][d][s] = transpose of chi[b][s][d]  (bf16 -> bf16, via LDS)
// ---------------------------------------------------------------------------
__global__ __launch_bounds__(256) void t_chi(const unsigned short* __restrict__ H,
                                             unsigned short* __restrict__ T) {
  __shared__ unsigned short L[64][72];
  const int t = threadIdx.x;
  const int d0 = blockIdx.x * 64, s0 = blockIdx.y * 64, b = blockIdx.z;
  const int sl = t >> 2, dp = (t & 3) * 16;
  short8 v0 = *(const short8*)&H[((size_t)b * SEQ + s0 + sl) * DIM + d0 + dp];
  short8 v1 = *(const short8*)&H[((size_t)b * SEQ + s0 + sl) * DIM + d0 + dp + 8];
  *(short8*)&L[sl][dp] = v0;
  *(short8*)&L[sl][dp + 8] = v1;
  __syncthreads();
  const int dl = t >> 2, sp = (t & 3) * 16;
  short8 o0, o1;
#pragma unroll
  for (int k = 0; k < 8; ++k) {
    o0[k] = (short)L[sp + k][dl];
    o1[k] = (short)L[sp + 8 + k][dl];
  }
  *(short8*)&T[((size_t)b * DIM + d0 + dl) * SEQ + s0 + sp] = o0;
  *(short8*)&T[((size_t)b * DIM + d0 + dl) * SEQ + s0 + sp + 8] = o1;
}

// ---------------------------------------------------------------------------
// G1: z[r][d] = sum_e query[r][e] * W[d][e]  (R6-proven)
// ---------------------------------------------------------------------------
__global__ __launch_bounds__(256) void g1_z(const float* __restrict__ Q,
                                            const float* __restrict__ W,
                                            unsigned short* __restrict__ zhi,
                                            unsigned short* __restrict__ zlo) {
  __shared__ unsigned short Ah[128 * LDST], Al[128 * LDST];
  __shared__ unsigned short Bh[128 * LDST], Bl[128 * LDST];
  const int tid = threadIdx.x;
  const int m0 = blockIdx.y * 128, n0 = blockIdx.x * 128;
  const int wave = tid >> 6, lane = tid & 63;
  const int wm = (wave >> 1) * 64, wn = (wave & 1) * 64;
  const int rl = tid & 127;

  const float* srow = (tid < 128) ? Q + (size_t)(m0 + rl) * DIM
                                  : W + (size_t)(n0 + rl) * DIM;
  unsigned short* th = (tid < 128) ? Ah : Bh;
  unsigned short* tl = (tid < 128) ? Al : Bl;

  f32x4 acc[4][4];
#pragma unroll
  for (int i = 0; i < 4; ++i)
#pragma unroll
    for (int j = 0; j < 4; ++j) acc[i][j] = (f32x4){0.f, 0.f, 0.f, 0.f};

  for (int kc = 0; kc < DIM; kc += 32) {
    float4 fv[8];
#pragma unroll
    for (int j = 0; j < 8; ++j) fv[j] = *(const float4*)&srow[kc + j * 4];
    __syncthreads();
    short8 hv[4], lv[4];
#pragma unroll
    for (int j = 0; j < 8; ++j) {
      const float x[4] = {fv[j].x, fv[j].y, fv[j].z, fv[j].w};
#pragma unroll
      for (int c = 0; c < 4; ++c) {
        unsigned short h = f2bf(x[c]);
        unsigned short l = f2bf(x[c] - bf2f(h));
        hv[j >> 1][(j & 1) * 4 + c] = (short)h;
        lv[j >> 1][(j & 1) * 4 + c] = (short)l;
      }
    }
#pragma unroll
    for (int j = 0; j < 4; ++j) {
      *(short8*)&th[rl * LDST + j * 8] = hv[j];
      *(short8*)&tl[rl * LDST + j * 8] = lv[j];
    }
    __syncthreads();

    short8 ah[4], al[4], bh[4], bl[4];
#pragma unroll
    for (int f = 0; f < 4; ++f) {
      const int ao = (wm + f * 16 + (lane & 15)) * LDST + (lane >> 4) * 8;
      const int bo = (wn + f * 16 + (lane & 15)) * LDST + (lane >> 4) * 8;
      ah[f] = *(const short8*)&Ah[ao];  al[f] = *(const short8*)&Al[ao];
      bh[f] = *(const short8*)&Bh[bo];  bl[f] = *(const short8*)&Bl[bo];
    }
#pragma unroll
    for (int i = 0; i < 4; ++i)
#pragma unroll
      for (int j = 0; j < 4; ++j) {
        acc[i][j] = __builtin_amdgcn_mfma_f32_16x16x32_bf16(ah[i], bh[j], acc[i][j], 0, 0, 0);
        acc[i][j] = __builtin_amdgcn_mfma_f32_16x16x32_bf16(al[i], bh[j], acc[i][j], 0, 0, 0);
        acc[i][j] = __builtin_amdgcn_mfma_f32_16x16x32_bf16(ah[i], bl[j], acc[i][j], 0, 0, 0);
      }
  }
#pragma unroll
  for (int i = 0; i < 4; ++i)
#pragma unroll
    for (int j = 0; j < 4; ++j)
#pragma unroll
      for (int r = 0; r < 4; ++r) {
        const int row = m0 + wm + i * 16 + (lane >> 4) * 4 + r;
        const int col = n0 + wn + j * 16 + (lane & 15);
        const float v = acc[i][j][r];
        const unsigned short h = f2bf(v);
        zhi[(size_t)row * DIM + col] = h;
        zlo[(size_t)row * DIM + col] = f2bf(v - bf2f(h));
      }
}

// ---------------------------------------------------------------------------
// G2 (R6-proven, 128x128, 2-barrier, XOR-swizzled): scores = z . ctx^T
// ---------------------------------------------------------------------------
#define G2GRID (16 * 16 * B_)
__global__ __launch_bounds__(256) void g2_scores(const unsigned short* __restrict__ zhi,
                                                 const unsigned short* __restrict__ zlo,
                                                 const unsigned short* __restrict__ chi,
                                                 const unsigned short* __restrict__ clo,
                                                 float* __restrict__ Sc) {
  __shared__ unsigned short Sh[128 * 32], Sl[128 * 32];   // ctx tiles (s-rows)
  __shared__ unsigned short Qh[128 * 32], Ql[128 * 32];   // z tiles (q-rows)
  const int tid = threadIdx.x, lane = tid & 63, wave = tid >> 6;

  const int lin = blockIdx.x;
  const int swz = (lin & 7) * (G2GRID / 8) + (lin >> 3);
  const int s0 = (swz & 15) * 128;
  const int q0 = ((swz >> 4) & 15) * 128;
  const int b  = swz >> 8;

  const int wm = (wave >> 1) * 64;   // s
  const int wn = (wave & 1) * 64;    // q

  const int r_sub = lane >> 2;                              // row within 16-row chunk
  const int c_sub = (((lane & 3) ^ ((lane >> 3) & 3))) * 8; // swizzled 16B block

  f32x4 acc[4][4];
#pragma unroll
  for (int i = 0; i < 4; ++i)
#pragma unroll
    for (int j = 0; j < 4; ++j) acc[i][j] = (f32x4){0.f, 0.f, 0.f, 0.f};

  for (int kc = 0; kc < DIM; kc += 32) {
    if (wave == 0) {
#pragma unroll
      for (int it = 0; it < 8; ++it)
        gl16(&chi[((size_t)b * SEQ + s0 + it * 16 + r_sub) * DIM + kc + c_sub], &Sh[it * 512]);
    } else if (wave == 1) {
#pragma unroll
      for (int it = 0; it < 8; ++it)
        gl16(&clo[((size_t)b * SEQ + s0 + it * 16 + r_sub) * DIM + kc + c_sub], &Sl[it * 512]);
    } else if (wave == 2) {
#pragma unroll
      for (int it = 0; it < 8; ++it)
        gl16(&zhi[((size_t)(q0 + it * 16 + r_sub) * B_ + b) * DIM + kc + c_sub], &Qh[it * 512]);
    } else {
#pragma unroll
      for (int it = 0; it < 8; ++it)
        gl16(&zlo[((size_t)(q0 + it * 16 + r_sub) * B_ + b) * DIM + kc + c_sub], &Ql[it * 512]);
    }
    __syncthreads();

    short8 sh_[4], sl_[4], qh_[4], ql_[4];
#pragma unroll
    for (int f = 0; f < 4; ++f) {
      const int ra = wm + f * 16 + (lane & 15);
      const int rb = wn + f * 16 + (lane & 15);
      const int so = ra * 32 + (((lane >> 4) ^ ((ra >> 1) & 3))) * 8;
      const int qo = rb * 32 + (((lane >> 4) ^ ((rb >> 1) & 3))) * 8;
      sh_[f] = *(const short8*)&Sh[so];  sl_[f] = *(const short8*)&Sl[so];
      qh_[f] = *(const short8*)&Qh[qo];  ql_[f] = *(const short8*)&Ql[qo];
    }
#pragma unroll
    for (int i = 0; i < 4; ++i)
#pragma unroll
      for (int j = 0; j < 4; ++j) {
        acc[i][j] = __builtin_amdgcn_mfma_f32_16x16x32_bf16(sh_[i], qh_[j], acc[i][j], 0, 0, 0);
        acc[i][j] = __builtin_amdgcn_mfma_f32_16x16x32_bf16(sl_[i], qh_[j], acc[i][j], 0, 0, 0);
        acc[i][j] = __builtin_amdgcn_mfma_f32_16x16x32_bf16(sh_[i], ql_[j], acc[i][j], 0, 0, 0);
      }
    __syncthreads();
  }

#pragma unroll
  for (int i = 0; i < 4; ++i)
#pragma unroll
    for (int j = 0; j < 4; ++j) {
      const int s = s0 + wm + i * 16 + (lane >> 4) * 4;
      const int q = q0 + wn + j * 16 + (lane & 15);
      f32x4 v = {acc[i][j][0], acc[i][j][1], acc[i][j][2], acc[i][j][3]};
      __builtin_nontemporal_store(v, (f32x4*)&Sc[((size_t)q * B_ + b) * SEQ + s]);
    }
}

// ---------------------------------------------------------------------------
// softmax: in-place, float4-vectorized
// ---------------------------------------------------------------------------
__global__ __launch_bounds__(256) void kernel_softmax(float* __restrict__ attn,
                                                      const int* __restrict__ mask) {
  const int row = blockIdx.x;       // q*B_ + b
  const int b = row & (B_ - 1);
  float* p = attn + (size_t)row * SEQ;
  const int* m = mask + (size_t)b * SEQ;
  const int t = threadIdx.x;

  float4 va = *(const float4*)&p[t * 8];
  float4 vb = *(const float4*)&p[t * 8 + 4];
  int4 ma = *(const int4*)&m[t * 8];
  int4 mb = *(const int4*)&m[t * 8 + 4];
  float v[8] = {ma.x ? -1e30f : va.x, ma.y ? -1e30f : va.y,
                ma.z ? -1e30f : va.z, ma.w ? -1e30f : va.w,
                mb.x ? -1e30f : vb.x, mb.y ? -1e30f : vb.y,
                mb.z ? -1e30f : vb.z, mb.w ? -1e30f : vb.w};
  float mx = -INFINITY;
#pragma unroll
  for (int i = 0; i < 8; ++i) mx = fmaxf(mx, v[i]);
#pragma unroll
  for (int off = 32; off > 0; off >>= 1) mx = fmaxf(mx, __shfl_xor(mx, off));
  __shared__ float redmax[4];
  __shared__ float redsum[4];
  if ((t & 63) == 0) redmax[t >> 6] = mx;
  __syncthreads();
  mx = fmaxf(fmaxf(redmax[0], redmax[1]), fmaxf(redmax[2], redmax[3]));

  float sum = 0.f;
#pragma unroll
  for (int i = 0; i < 8; ++i) {
    v[i] = __expf(v[i] - mx);
    sum += v[i];
  }
#pragma unroll
  for (int off = 32; off > 0; off >>= 1) sum += __shfl_xor(sum, off);
  if ((t & 63) == 0) redsum[t >> 6] = sum;
  __syncthreads();
  sum = (redsum[0] + redsum[1]) + (redsum[2] + redsum[3]);

  const bool allmasked = (mx < -1e29f);
  const float inv = allmasked ? 0.f : 1.f / sum;
  float4 oa = {v[0] * inv, v[1] * inv, v[2] * inv, v[3] * inv};
  float4 ob = {v[4] * inv, v[5] * inv, v[6] * inv, v[7] * inv};
  *(float4*)&p[t * 8] = oa;
  *(float4*)&p[t * 8 + 4] = ob;
}

// ---------------------------------------------------------------------------
// G3 (BK=64, st_16x32 swizzle): comp[q][b][d] = sum_s attn[q][b][s]*ctx[b][s][d]
// A = ctxT d-rows via gl16 with pre-swizzled SOURCE block (L[r][blk]=G[r][blk^r&7]);
// B = attn f32 coalesced -> bf16 -> swizzled ds_write. Frag read: blk = kb^(r&7).
// 32 MFMA : 16 ds_read per wave-step, 32 K-steps (barriers halved vs BK=32).
// ---------------------------------------------------------------------------
__global__ __launch_bounds__(256) void g3_comp(const float* __restrict__ attn,
                                               const unsigned short* __restrict__ ctxT,
                                               float* __restrict__ Out) {
  __shared__ unsigned short Ad[128 * 64];   // ctxT tile (d-rows, 128B rows, swz)
  __shared__ unsigned short Bq[128 * 64];   // attn tile (q-rows, bf16, swz)
  const int tid = threadIdx.x, lane = tid & 63, wave = tid >> 6;
  const int b = blockIdx.z;
  const int d0 = blockIdx.x * 128, q0 = blockIdx.y * 128;
  const int wm = (wave >> 1) * 64;   // d
  const int wn = (wave & 1) * 64;    // q

  // A staging: wave stages d-rows [wave*32, wave*32+32), 4 gl16 x (8 rows each)
  const int r8 = lane >> 3;                 // row within 8-row group
  const int c8 = lane & 7;                  // 16B block 0..7
  const unsigned short* agp =
      ctxT + ((size_t)b * DIM + d0 + wave * 32 + r8) * SEQ + (size_t)((c8 ^ r8) * 8);

  // B staging: thread t -> q-row t>>1, s-half (t&1)*32 floats
  const int qrow = tid >> 1;
  const int rk = qrow & 7;
  const float* arow = attn + ((size_t)(q0 + qrow) * B_ + b) * SEQ + (tid & 1) * 32;

  f32x4 acc[4][4];
#pragma unroll
  for (int i = 0; i < 4; ++i)
#pragma unroll
    for (int j = 0; j < 4; ++j) acc[i][j] = (f32x4){0.f, 0.f, 0.f, 0.f};

  for (int kc = 0; kc < SEQ; kc += 64) {
    // B: 32 f32 loads (coalesced float4)
    float4 fv[8];
#pragma unroll
    for (int jj = 0; jj < 8; ++jj) fv[jj] = *(const float4*)&arow[kc + jj * 4];
    // A: 4 gl16 (pre-swizzled source)
#pragma unroll
    for (int g = 0; g < 4; ++g)
      gl16(agp + (size_t)g * 8 * SEQ + kc, &Ad[(wave * 32 + g * 8) * 64]);
    // cvt + swizzled ds_write (4 x short8)
#pragma unroll
    for (int jw = 0; jw < 4; ++jw) {
      short8 w;
#pragma unroll
      for (int e = 0; e < 8; ++e) {
        const float4 f4 = fv[jw * 2 + (e >> 2)];
        const float x = (e & 3) == 0 ? f4.x : (e & 3) == 1 ? f4.y : (e & 3) == 2 ? f4.z : f4.w;
        w[e] = (short)f2bf(x);
      }
      const int blk = (tid & 1) * 4 + jw;
      *(short8*)&Bq[qrow * 64 + ((blk ^ rk)) * 8] = w;
    }
    __syncthreads();

    short8 af[4][2], bf_[4][2];
#pragma unroll
    for (int f = 0; f < 4; ++f) {
      const int ra = wm + f * 16 + (lane & 15);
      const int rb = wn + f * 16 + (lane & 15);
#pragma unroll
      for (int h = 0; h < 2; ++h) {
        const int kbA = h * 4 + (lane >> 4);
        af[f][h]  = *(const short8*)&Ad[ra * 64 + ((kbA ^ (ra & 7))) * 8];
        bf_[f][h] = *(const short8*)&Bq[rb * 64 + ((kbA ^ (rb & 7))) * 8];
      }
    }
#pragma unroll
    for (int i = 0; i < 4; ++i)
#pragma unroll
      for (int j = 0; j < 4; ++j) {
        acc[i][j] = __builtin_amdgcn_mfma_f32_16x16x32_bf16(af[i][0], bf_[j][0], acc[i][j], 0, 0, 0);
        acc[i][j] = __builtin_amdgcn_mfma_f32_16x16x32_bf16(af[i][1], bf_[j][1], acc[i][j], 0, 0, 0);
      }
    __syncthreads();
  }

#pragma unroll
  for (int i = 0; i < 4; ++i)
#pragma unroll
    for (int j = 0; j < 4; ++j) {
      const int d = d0 + wm + i * 16 + (lane >> 4) * 4;
      const int q = q0 + wn + j * 16 + (lane & 15);
      f32x4 v = {acc[i][j][0], acc[i][j][1], acc[i][j][2], acc[i][j][3]};
      __builtin_nontemporal_store(v, (f32x4*)&Out[((size_t)q * B_ + b) * DIM + d]);
    }
}

extern "C" void kernel_launch(void* const* d_in, const int* in_sizes, int n_in,
                              void* d_out, int out_size, void* d_ws, size_t ws_size,
                              hipStream_t stream) {
  const float* context = (const float*)d_in[0];   // [B, SEQ, DIM]
  const float* query   = (const float*)d_in[1];   // [SEQ, B, DIM]
  const float* W       = (const float*)d_in[2];   // [DIM, DIM]
  const int*   mask    = (const int*)d_in[3];     // [B, SEQ] bool->int32

  float* attn = (float*)d_out;                     // [SEQ, B, SEQ]  (256 MiB)
  float* comp = attn + (size_t)SEQ * B_ * SEQ;     // [SEQ, B, DIM]  (128 MiB)

  unsigned short* chi = (unsigned short*)comp;                     // 64 MiB
  unsigned short* clo = chi + (size_t)B_ * SEQ * DIM;              // 64 MiB

  unsigned short* zhi  = (unsigned short*)d_ws;                    // 64 MiB
  unsigned short* zlo  = zhi + (size_t)SEQ * B_ * DIM;             // 64 MiB
  unsigned short* ctxT = (unsigned short*)d_ws;                    // reuses z after G2

  // 0) ctx -> bf16 hi/lo planes (comp region; dead until G3 overwrites)
  cvt_ctx<<<dim3(4096), 256, 0, stream>>>(context, chi, clo);
  // 1) z = W @ query (flat rows), bf16x2
  g1_z<<<dim3(DIM / 128, (SEQ * B_) / 128), 256, 0, stream>>>(query, W, zhi, zlo);
  // 2) scores -> attn region (R6-proven 128^2 2-barrier)
  g2_scores<<<dim3(G2GRID), 256, 0, stream>>>(zhi, zlo, chi, clo, attn);
  // 2b) ctxT = transpose(chi) into d_ws (z dead now)
  t_chi<<<dim3(DIM / 64, SEQ / 64, B_), 256, 0, stream>>>(chi, ctxT);
  // 3) masked softmax in place
  kernel_softmax<<<dim3(SEQ * B_), 256, 0, stream>>>(attn, mask);
  // 4) comp = attn @ ctx via ctxT (BK=64, st_16x32 swizzle)
  g3_comp<<<dim3(DIM / 128, SEQ / 128, B_), 256, 0, stream>>>(attn, ctxT, comp);
}

// Round 13
// 1080.238 us; speedup vs baseline: 1.3550x; 1.2105x over previous
//
#include <hip/hip_runtime.h>
#include <cmath>

#define B_  16
#define SEQ 2048
#define DIM 1024

typedef short  short8 __attribute__((ext_vector_type(8)));
typedef short  sh4    __attribute__((ext_vector_type(4)));
typedef float  f32x4  __attribute__((ext_vector_type(4)));

__device__ __forceinline__ unsigned short f2bf(float x) {
  unsigned u = __builtin_bit_cast(unsigned, x);
  return (unsigned short)((u + 0x7fffu + ((u >> 16) & 1u)) >> 16);   // RNE
}
__device__ __forceinline__ float bf2f(unsigned short h) {
  unsigned u = ((unsigned)h) << 16;
  return __builtin_bit_cast(float, u);
}

__device__ __forceinline__ void gl16(const void* g, void* l) {
  __builtin_amdgcn_global_load_lds(
      (const __attribute__((address_space(1))) void*)g,
      (__attribute__((address_space(3))) void*)l, 16, 0, 0);
}

// ---------------------------------------------------------------------------
// cvt_split: f32 [B*SEQ*DIM] -> bf16 hi/lo planes (context AND query)
// ---------------------------------------------------------------------------
__global__ __launch_bounds__(256) void cvt_split(const float* __restrict__ X,
                                                 unsigned short* __restrict__ hi,
                                                 unsigned short* __restrict__ lo) {
  const size_t N8 = (size_t)B_ * SEQ * DIM / 8;
  for (size_t i = (size_t)blockIdx.x * 256 + threadIdx.x; i < N8;
       i += (size_t)gridDim.x * 256) {
    const size_t base = i * 8;
    float4 a = *(const float4*)&X[base];
    float4 c = *(const float4*)&X[base + 4];
    const float xs[8] = {a.x, a.y, a.z, a.w, c.x, c.y, c.z, c.w};
    short8 h, l;
#pragma unroll
    for (int j = 0; j < 8; ++j) {
      unsigned short hh = f2bf(xs[j]);
      h[j] = (short)hh;
      l[j] = (short)f2bf(xs[j] - bf2f(hh));
    }
    *(short8*)&hi[base] = h;
    *(short8*)&lo[base] = l;
  }
}

// ---------------------------------------------------------------------------
// cvt_w: W[d][e] f32 -> wh[d][e], wl[d][e] bf16 hi/lo.  PURE SPLIT, NO
// TRANSPOSE (W's first index d contracts with ctx; B-rows of g1 are W rows).
// ---------------------------------------------------------------------------
__global__ __launch_bounds__(256) void cvt_w(const float* __restrict__ X,
                                             unsigned short* __restrict__ hi,
                                             unsigned short* __restrict__ lo) {
  const size_t N8 = (size_t)DIM * DIM / 8;
  for (size_t i = (size_t)blockIdx.x * 256 + threadIdx.x; i < N8;
       i += (size_t)gridDim.x * 256) {
    const size_t base = i * 8;
    float4 a = *(const float4*)&X[base];
    float4 c = *(const float4*)&X[base + 4];
    const float xs[8] = {a.x, a.y, a.z, a.w, c.x, c.y, c.z, c.w};
    short8 h, l;
#pragma unroll
    for (int j = 0; j < 8; ++j) {
      unsigned short hh = f2bf(xs[j]);
      h[j] = (short)hh;
      l[j] = (short)f2bf(xs[j] - bf2f(hh));
    }
    *(short8*)&hi[base] = h;
    *(short8*)&lo[base] = l;
  }
}

// ---------------------------------------------------------------------------
// t_chi: ctxT[b][d][s] = transpose of chi[b][s][d]  (bf16 -> bf16, via LDS)
// ---------------------------------------------------------------------------
__global__ __launch_bounds__(256) void t_chi(const unsigned short* __restrict__ H,
                                             unsigned short* __restrict__ T) {
  __shared__ unsigned short L[64][72];
  const int t = threadIdx.x;
  const int d0 = blockIdx.x * 64, s0 = blockIdx.y * 64, b = blockIdx.z;
  const int sl = t >> 2, dp = (t & 3) * 16;
  short8 v0 = *(const short8*)&H[((size_t)b * SEQ + s0 + sl) * DIM + d0 + dp];
  short8 v1 = *(const short8*)&H[((size_t)b * SEQ + s0 + sl) * DIM + d0 + dp + 8];
  *(short8*)&L[sl][dp] = v0;
  *(short8*)&L[sl][dp + 8] = v1;
  __syncthreads();
  const int dl = t >> 2, sp = (t & 3) * 16;
  short8 o0, o1;
#pragma unroll
  for (int k = 0; k < 8; ++k) {
    o0[k] = (short)L[sp + k][dl];
    o1[k] = (short)L[sp + 8 + k][dl];
  }
  *(short8*)&T[((size_t)b * DIM + d0 + dl) * SEQ + s0 + sp] = o0;
  *(short8*)&T[((size_t)b * DIM + d0 + dl) * SEQ + s0 + sp + 8] = o1;
}

// ---------------------------------------------------------------------------
// G1 (m97-clone): z[r][d] = sum_e q[r][e] * W[d][e], 4 planes pure-gl16.
// M = 32768 (q-rows), N = 1024 (W d-rows), K = 1024. 48 MFMA/wave-step.
// ---------------------------------------------------------------------------
#define G1GRID 2048    // 256 m-tiles x 8 n-tiles
__global__ __launch_bounds__(256) void g1_z(const unsigned short* __restrict__ qh,
                                            const unsigned short* __restrict__ ql,
                                            const unsigned short* __restrict__ wh,
                                            const unsigned short* __restrict__ wl,
                                            unsigned short* __restrict__ zhi,
                                            unsigned short* __restrict__ zlo) {
  __shared__ unsigned short Ah[128 * 32], Al[128 * 32];
  __shared__ unsigned short Bh[128 * 32], Bl[128 * 32];
  const int tid = threadIdx.x, lane = tid & 63, wave = tid >> 6;

  const int lin = blockIdx.x;
  const int swz = (lin & 7) * (G1GRID / 8) + (lin >> 3);
  const int m0 = (swz >> 3) * 128;
  const int n0 = (swz & 7) * 128;

  const int wm = (wave >> 1) * 64;   // m (z-row)
  const int wn = (wave & 1) * 64;    // n (d)

  const int r_sub = lane >> 2;
  const int c_sub = (((lane & 3) ^ ((lane >> 3) & 3))) * 8;

  f32x4 acc[4][4];
#pragma unroll
  for (int i = 0; i < 4; ++i)
#pragma unroll
    for (int j = 0; j < 4; ++j) acc[i][j] = (f32x4){0.f, 0.f, 0.f, 0.f};

  for (int kc = 0; kc < DIM; kc += 32) {
    if (wave == 0) {
#pragma unroll
      for (int it = 0; it < 8; ++it)
        gl16(&qh[(size_t)(m0 + it * 16 + r_sub) * DIM + kc + c_sub], &Ah[it * 512]);
    } else if (wave == 1) {
#pragma unroll
      for (int it = 0; it < 8; ++it)
        gl16(&ql[(size_t)(m0 + it * 16 + r_sub) * DIM + kc + c_sub], &Al[it * 512]);
    } else if (wave == 2) {
#pragma unroll
      for (int it = 0; it < 8; ++it)
        gl16(&wh[(size_t)(n0 + it * 16 + r_sub) * DIM + kc + c_sub], &Bh[it * 512]);
    } else {
#pragma unroll
      for (int it = 0; it < 8; ++it)
        gl16(&wl[(size_t)(n0 + it * 16 + r_sub) * DIM + kc + c_sub], &Bl[it * 512]);
    }
    __syncthreads();

    short8 ah[4], al[4], bh[4], bl[4];
#pragma unroll
    for (int f = 0; f < 4; ++f) {
      const int ra = wm + f * 16 + (lane & 15);
      const int rb = wn + f * 16 + (lane & 15);
      const int ao = ra * 32 + (((lane >> 4) ^ ((ra >> 1) & 3))) * 8;
      const int bo = rb * 32 + (((lane >> 4) ^ ((rb >> 1) & 3))) * 8;
      ah[f] = *(const short8*)&Ah[ao];  al[f] = *(const short8*)&Al[ao];
      bh[f] = *(const short8*)&Bh[bo];  bl[f] = *(const short8*)&Bl[bo];
    }
#pragma unroll
    for (int i = 0; i < 4; ++i)
#pragma unroll
      for (int j = 0; j < 4; ++j) {
        acc[i][j] = __builtin_amdgcn_mfma_f32_16x16x32_bf16(ah[i], bh[j], acc[i][j], 0, 0, 0);
        acc[i][j] = __builtin_amdgcn_mfma_f32_16x16x32_bf16(al[i], bh[j], acc[i][j], 0, 0, 0);
        acc[i][j] = __builtin_amdgcn_mfma_f32_16x16x32_bf16(ah[i], bl[j], acc[i][j], 0, 0, 0);
      }
    __syncthreads();
  }

#pragma unroll
  for (int i = 0; i < 4; ++i)
#pragma unroll
    for (int j = 0; j < 4; ++j)
#pragma unroll
      for (int r = 0; r < 4; ++r) {
        const int row = m0 + wm + i * 16 + (lane >> 4) * 4 + r;
        const int col = n0 + wn + j * 16 + (lane & 15);
        const float v = acc[i][j][r];
        const unsigned short h = f2bf(v);
        zhi[(size_t)row * DIM + col] = h;
        zlo[(size_t)row * DIM + col] = f2bf(v - bf2f(h));
      }
}

// ---------------------------------------------------------------------------
// G2 (R6-proven, 128x128, 2-barrier, XOR-swizzled): scores = z . ctx^T
// ---------------------------------------------------------------------------
#define G2GRID (16 * 16 * B_)
__global__ __launch_bounds__(256) void g2_scores(const unsigned short* __restrict__ zhi,
                                                 const unsigned short* __restrict__ zlo,
                                                 const unsigned short* __restrict__ chi,
                                                 const unsigned short* __restrict__ clo,
                                                 float* __restrict__ Sc) {
  __shared__ unsigned short Sh[128 * 32], Sl[128 * 32];   // ctx tiles (s-rows)
  __shared__ unsigned short Qh[128 * 32], Ql[128 * 32];   // z tiles (q-rows)
  const int tid = threadIdx.x, lane = tid & 63, wave = tid >> 6;

  const int lin = blockIdx.x;
  const int swz = (lin & 7) * (G2GRID / 8) + (lin >> 3);
  const int s0 = (swz & 15) * 128;
  const int q0 = ((swz >> 4) & 15) * 128;
  const int b  = swz >> 8;

  const int wm = (wave >> 1) * 64;   // s
  const int wn = (wave & 1) * 64;    // q

  const int r_sub = lane >> 2;
  const int c_sub = (((lane & 3) ^ ((lane >> 3) & 3))) * 8;

  f32x4 acc[4][4];
#pragma unroll
  for (int i = 0; i < 4; ++i)
#pragma unroll
    for (int j = 0; j < 4; ++j) acc[i][j] = (f32x4){0.f, 0.f, 0.f, 0.f};

  for (int kc = 0; kc < DIM; kc += 32) {
    if (wave == 0) {
#pragma unroll
      for (int it = 0; it < 8; ++it)
        gl16(&chi[((size_t)b * SEQ + s0 + it * 16 + r_sub) * DIM + kc + c_sub], &Sh[it * 512]);
    } else if (wave == 1) {
#pragma unroll
      for (int it = 0; it < 8; ++it)
        gl16(&clo[((size_t)b * SEQ + s0 + it * 16 + r_sub) * DIM + kc + c_sub], &Sl[it * 512]);
    } else if (wave == 2) {
#pragma unroll
      for (int it = 0; it < 8; ++it)
        gl16(&zhi[((size_t)(q0 + it * 16 + r_sub) * B_ + b) * DIM + kc + c_sub], &Qh[it * 512]);
    } else {
#pragma unroll
      for (int it = 0; it < 8; ++it)
        gl16(&zlo[((size_t)(q0 + it * 16 + r_sub) * B_ + b) * DIM + kc + c_sub], &Ql[it * 512]);
    }
    __syncthreads();

    short8 sh_[4], sl_[4], qh_[4], ql_[4];
#pragma unroll
    for (int f = 0; f < 4; ++f) {
      const int ra = wm + f * 16 + (lane & 15);
      const int rb = wn + f * 16 + (lane & 15);
      const int so = ra * 32 + (((lane >> 4) ^ ((ra >> 1) & 3))) * 8;
      const int qo = rb * 32 + (((lane >> 4) ^ ((rb >> 1) & 3))) * 8;
      sh_[f] = *(const short8*)&Sh[so];  sl_[f] = *(const short8*)&Sl[so];
      qh_[f] = *(const short8*)&Qh[qo];  ql_[f] = *(const short8*)&Ql[qo];
    }
#pragma unroll
    for (int i = 0; i < 4; ++i)
#pragma unroll
      for (int j = 0; j < 4; ++j) {
        acc[i][j] = __builtin_amdgcn_mfma_f32_16x16x32_bf16(sh_[i], qh_[j], acc[i][j], 0, 0, 0);
        acc[i][j] = __builtin_amdgcn_mfma_f32_16x16x32_bf16(sl_[i], qh_[j], acc[i][j], 0, 0, 0);
        acc[i][j] = __builtin_amdgcn_mfma_f32_16x16x32_bf16(sh_[i], ql_[j], acc[i][j], 0, 0, 0);
      }
    __syncthreads();
  }

#pragma unroll
  for (int i = 0; i < 4; ++i)
#pragma unroll
    for (int j = 0; j < 4; ++j) {
      const int s = s0 + wm + i * 16 + (lane >> 4) * 4;
      const int q = q0 + wn + j * 16 + (lane & 15);
      f32x4 v = {acc[i][j][0], acc[i][j][1], acc[i][j][2], acc[i][j][3]};
      __builtin_nontemporal_store(v, (f32x4*)&Sc[((size_t)q * B_ + b) * SEQ + s]);
    }
}

// ---------------------------------------------------------------------------
// softmax: in-place + bf16 side copy to attnb[b][q][s]
// ---------------------------------------------------------------------------
__global__ __launch_bounds__(256) void kernel_softmax(float* __restrict__ attn,
                                                      const int* __restrict__ mask,
                                                      unsigned short* __restrict__ attnb) {
  const int row = blockIdx.x;       // q*B_ + b
  const int b = row & (B_ - 1);
  const int q = row >> 4;
  float* p = attn + (size_t)row * SEQ;
  const int* m = mask + (size_t)b * SEQ;
  unsigned short* pb = attnb + ((size_t)b * SEQ + q) * SEQ;
  const int t = threadIdx.x;

  float4 va = *(const float4*)&p[t * 8];
  float4 vb = *(const float4*)&p[t * 8 + 4];
  int4 ma = *(const int4*)&m[t * 8];
  int4 mb = *(const int4*)&m[t * 8 + 4];
  float v[8] = {ma.x ? -1e30f : va.x, ma.y ? -1e30f : va.y,
                ma.z ? -1e30f : va.z, ma.w ? -1e30f : va.w,
                mb.x ? -1e30f : vb.x, mb.y ? -1e30f : vb.y,
                mb.z ? -1e30f : vb.z, mb.w ? -1e30f : vb.w};
  float mx = -INFINITY;
#pragma unroll
  for (int i = 0; i < 8; ++i) mx = fmaxf(mx, v[i]);
#pragma unroll
  for (int off = 32; off > 0; off >>= 1) mx = fmaxf(mx, __shfl_xor(mx, off));
  __shared__ float redmax[4];
  __shared__ float redsum[4];
  if ((t & 63) == 0) redmax[t >> 6] = mx;
  __syncthreads();
  mx = fmaxf(fmaxf(redmax[0], redmax[1]), fmaxf(redmax[2], redmax[3]));

  float sum = 0.f;
#pragma unroll
  for (int i = 0; i < 8; ++i) {
    v[i] = __expf(v[i] - mx);
    sum += v[i];
  }
#pragma unroll
  for (int off = 32; off > 0; off >>= 1) sum += __shfl_xor(sum, off);
  if ((t & 63) == 0) redsum[t >> 6] = sum;
  __syncthreads();
  sum = (redsum[0] + redsum[1]) + (redsum[2] + redsum[3]);

  const bool allmasked = (mx < -1e29f);
  const float inv = allmasked ? 0.f : 1.f / sum;
  float o[8];
  short8 ob16;
#pragma unroll
  for (int i = 0; i < 8; ++i) {
    o[i] = v[i] * inv;
    ob16[i] = (short)f2bf(o[i]);
  }
  float4 oa = {o[0], o[1], o[2], o[3]};
  float4 ob = {o[4], o[5], o[6], o[7]};
  *(float4*)&p[t * 8] = oa;
  *(float4*)&p[t * 8 + 4] = ob;
  *(short8*)&pb[t * 8] = ob16;
}

// ---------------------------------------------------------------------------
// G3 (2-plane pure-gl16, BK=64, st_16x32): comp[q][b][d] = sum_s attnb*ctxT
// A = ctxT d-rows, B = attnb q-rows, both staged via gl16 with pre-swizzled
// source block (L[r][blk] = G[r][blk^(r&7)]); frag read blk = kb^(r&7).
// ---------------------------------------------------------------------------
__global__ __launch_bounds__(256) void g3_comp(const unsigned short* __restrict__ attnb,
                                               const unsigned short* __restrict__ ctxT,
                                               float* __restrict__ Out) {
  __shared__ unsigned short Ad[128 * 64];   // ctxT tile (d-rows)
  __shared__ unsigned short Bq[128 * 64];   // attnb tile (q-rows)
  const int tid = threadIdx.x, lane = tid & 63, wave = tid >> 6;
  const int b = blockIdx.z;
  const int d0 = blockIdx.x * 128, q0 = blockIdx.y * 128;
  const int wm = (wave >> 1) * 64;   // d
  const int wn = (wave & 1) * 64;    // q

  const int r8 = lane >> 3;          // row within 8-row granule
  const int c8 = lane & 7;           // 16B block
  const unsigned short* src;
  if (wave < 2)
    src = ctxT + ((size_t)b * DIM + d0 + wave * 64 + r8) * SEQ + (size_t)((c8 ^ r8) * 8);
  else
    src = attnb + ((size_t)b * SEQ + q0 + (wave - 2) * 64 + r8) * SEQ + (size_t)((c8 ^ r8) * 8);
  unsigned short* ldst = (wave < 2) ? &Ad[wave * 64 * 64] : &Bq[(wave - 2) * 64 * 64];

  f32x4 acc[4][4];
#pragma unroll
  for (int i = 0; i < 4; ++i)
#pragma unroll
    for (int j = 0; j < 4; ++j) acc[i][j] = (f32x4){0.f, 0.f, 0.f, 0.f};

  for (int kc = 0; kc < SEQ; kc += 64) {
#pragma unroll
    for (int g = 0; g < 8; ++g)
      gl16(src + (size_t)g * 8 * SEQ + kc, ldst + g * 8 * 64);
    __syncthreads();

    short8 af[4][2], bf_[4][2];
#pragma unroll
    for (int f = 0; f < 4; ++f) {
      const int ra = wm + f * 16 + (lane & 15);
      const int rb = wn + f * 16 + (lane & 15);
#pragma unroll
      for (int h = 0; h < 2; ++h) {
        const int kb = h * 4 + (lane >> 4);
        af[f][h]  = *(const short8*)&Ad[ra * 64 + ((kb ^ (ra & 7))) * 8];
        bf_[f][h] = *(const short8*)&Bq[rb * 64 + ((kb ^ (rb & 7))) * 8];
      }
    }
#pragma unroll
    for (int i = 0; i < 4; ++i)
#pragma unroll
      for (int j = 0; j < 4; ++j) {
        acc[i][j] = __builtin_amdgcn_mfma_f32_16x16x32_bf16(af[i][0], bf_[j][0], acc[i][j], 0, 0, 0);
        acc[i][j] = __builtin_amdgcn_mfma_f32_16x16x32_bf16(af[i][1], bf_[j][1], acc[i][j], 0, 0, 0);
      }
    __syncthreads();
  }

#pragma unroll
  for (int i = 0; i < 4; ++i)
#pragma unroll
    for (int j = 0; j < 4; ++j) {
      const int d = d0 + wm + i * 16 + (lane >> 4) * 4;
      const int q = q0 + wn + j * 16 + (lane & 15);
      f32x4 v = {acc[i][j][0], acc[i][j][1], acc[i][j][2], acc[i][j][3]};
      __builtin_nontemporal_store(v, (f32x4*)&Out[((size_t)q * B_ + b) * DIM + d]);
    }
}

extern "C" void kernel_launch(void* const* d_in, const int* in_sizes, int n_in,
                              void* d_out, int out_size, void* d_ws, size_t ws_size,
                              hipStream_t stream) {
  const float* context = (const float*)d_in[0];   // [B, SEQ, DIM]
  const float* query   = (const float*)d_in[1];   // [SEQ, B, DIM]
  const float* W       = (const float*)d_in[2];   // [DIM, DIM]  ([d][e])
  const int*   mask    = (const int*)d_in[3];     // [B, SEQ] bool->int32

  float* attn = (float*)d_out;                     // [SEQ, B, SEQ]  (256 MiB)
  float* comp = attn + (size_t)SEQ * B_ * SEQ;     // [SEQ, B, DIM]  (128 MiB)

  // comp region: ctx hi/lo planes (dead after t_chi; g3 overwrites at end)
  unsigned short* chi = (unsigned short*)comp;                     // 64 MiB
  unsigned short* clo = chi + (size_t)B_ * SEQ * DIM;              // 64 MiB

  // attn region (free until g2 writes it): query hi/lo + W hi/lo planes
  unsigned short* qh = (unsigned short*)attn;                      // 64 MiB
  unsigned short* ql = qh + (size_t)SEQ * B_ * DIM;                // 64 MiB
  unsigned short* wh = ql + (size_t)SEQ * B_ * DIM;                // 2 MiB
  unsigned short* wl = wh + (size_t)DIM * DIM;                     // 2 MiB

  // ws: z hi/lo for g1->g2; then ctxT + attnb reuse it after g2
  unsigned short* zhi   = (unsigned short*)d_ws;                   // 64 MiB
  unsigned short* zlo   = zhi + (size_t)SEQ * B_ * DIM;            // 64 MiB
  unsigned short* ctxT  = (unsigned short*)d_ws;                   // 64 MiB (after g2)
  unsigned short* attnb = zlo;                                     // 64 MiB (after g2)

  // 0) splits
  cvt_split<<<dim3(4096), 256, 0, stream>>>(context, chi, clo);
  cvt_split<<<dim3(4096), 256, 0, stream>>>(query, qh, ql);
  cvt_w<<<dim3(512), 256, 0, stream>>>(W, wh, wl);
  // 1) z = q . W-rows (m97-clone, pure gl16)
  g1_z<<<dim3(G1GRID), 256, 0, stream>>>(qh, ql, wh, wl, zhi, zlo);
  // 2) scores -> attn region (clobbers qh/ql/wh/wl, now dead)
  g2_scores<<<dim3(G2GRID), 256, 0, stream>>>(zhi, zlo, chi, clo, attn);
  // 2b) ctxT = transpose(chi) into ws (z dead after g2)
  t_chi<<<dim3(DIM / 64, SEQ / 64, B_), 256, 0, stream>>>(chi, ctxT);
  // 3) masked softmax in place + bf16 side copy into ws
  kernel_softmax<<<dim3(SEQ * B_), 256, 0, stream>>>(attn, mask, attnb);
  // 4) comp = attnb . ctxT (2-plane pure gl16, BK=64)
  g3_comp<<<dim3(DIM / 128, SEQ / 128, B_), 256, 0, stream>>>(attnb, ctxT, comp);
}